// Round 13
// baseline (506.848 us; speedup 1.0000x reference)
//
#include <hip/hip_runtime.h>

// RGCN 2-layer forward for MI355X (gfx950). N=50000, D=128, R=16, E=1600000.
//
// Round-21: coalesce the sort's scattered writes. R20 budget: gather 188us
// (roofline, closed) + gemm <=187 -> sort+conv+gaps >= 86us vs ~25us floor.
// fillA wrote 1.6M random 8B stores, fillB 1.6M random 4B stores - sub-line
// scatter costs ~8x logical bytes. Fix: LDS local-ordering so all global
// writes are linear: fillA stages pairs bucket-grouped (local prefix +
// delta[] = global_base - local_base), fillB stages the whole bucket's
// sorted_src in key order (SCAP=6144 > ~4400 worst case, with overflow
// fallback). Gather/gemm/conv identical to R20 (461.6us best).
//
// ws: h_bf | x_bf | Wt1 | Wt2 | seg_off | cnt_inv | sorted_src | ctl |
//     union( coarse_buf , msg(C*N*128 bf16) + acc(N*128 f32 if C<16) )

#define ND 128
#define NR 16
#define KPB 2048              // keys per coarse bucket
#define QI (KPB / 256)        // edge iters per block in hist/fillA
#define SCAP 6144             // fillB staging capacity (mean 4096, +32 sigma)

typedef __attribute__((ext_vector_type(8))) short bf16x8;
typedef __attribute__((ext_vector_type(4))) float f32x4;

__device__ __forceinline__ unsigned short f2b(float f) {
    unsigned u = __float_as_uint(f);
    u += 0x7FFFu + ((u >> 16) & 1u);          // round-to-nearest-even
    return (unsigned short)(u >> 16);
}

// async global->LDS, 16 bytes per lane (wave: 1 KB per instruction)
__device__ __forceinline__ void gload16(const unsigned short* g, unsigned short* l) {
    __builtin_amdgcn_global_load_lds(
        (__attribute__((address_space(1))) void*)g,
        (__attribute__((address_space(3))) void*)l, 16, 0, 0);
}

// ------------------------------------------------------------ coarse hist ---
__global__ __launch_bounds__(256) void coarse_hist(
    const int* __restrict__ dst, const int* __restrict__ rel,
    int* __restrict__ coarse_cnt, int E, int N, int NBK)
{
    __shared__ int h[1024];
    const int t = threadIdx.x;
    for (int i = t; i < NBK; i += 256) h[i] = 0;
    __syncthreads();
#pragma unroll
    for (int q = 0; q < QI; ++q) {
        int e = blockIdx.x * KPB + q * 256 + t;
        if (e < E) {
            int key = rel[e] * N + dst[e];
            atomicAdd(&h[key / KPB], 1);
        }
    }
    __syncthreads();
    for (int i = t; i < NBK; i += 256)
        if (h[i]) atomicAdd(&coarse_cnt[i], h[i]);
}

// ------------------------------------------------------------ coarse scan ---
__global__ __launch_bounds__(1024) void coarse_scan(
    const int* __restrict__ coarse_cnt, int* __restrict__ cscan,
    int* __restrict__ coarse_cursor, int NBK, int E)
{
    __shared__ int sdata[1024];
    const int t = threadIdx.x;
    int v = (t < NBK) ? coarse_cnt[t] : 0;
    sdata[t] = v;
    __syncthreads();
    for (int off = 1; off < 1024; off <<= 1) {
        int tmp = (t >= off) ? sdata[t - off] : 0;
        __syncthreads();
        sdata[t] += tmp;
        __syncthreads();
    }
    if (t < NBK) {
        int excl = sdata[t] - v;
        cscan[t] = excl;
        coarse_cursor[t] = excl;
    }
    if (t == 0) cscan[NBK] = E;
}

// --------------------------------------------------------- fill A (bucket) ---
// Stages pairs bucket-grouped in LDS so coarse_buf writes are coalesced runs.
__global__ __launch_bounds__(256) void fillA(
    const int* __restrict__ src, const int* __restrict__ dst,
    const int* __restrict__ rel, int* __restrict__ coarse_cursor,
    uint2* __restrict__ coarse_buf, int E, int N, int NBK)
{
    __shared__ uint2 pairs[KPB];     // 16 KB
    __shared__ uint2 staged[KPB];    // 16 KB
    __shared__ int h[1024];          // count -> local cursor
    __shared__ int delta[1024];      // global_base - local_base per bucket
    __shared__ int w[256];
    const int t = threadIdx.x;
    for (int i = t; i < 1024; i += 256) h[i] = 0;
    for (int j = t; j < KPB; j += 256) staged[j].y = 0xFFFFFFFFu;
    __syncthreads();
#pragma unroll
    for (int q = 0; q < QI; ++q) {
        int e = blockIdx.x * KPB + q * 256 + t;
        unsigned key = 0xFFFFFFFFu, sv = 0;
        if (e < E) {
            key = (unsigned)(rel[e] * N + dst[e]);
            sv = (unsigned)src[e];
            atomicAdd(&h[key / KPB], 1);
        }
        pairs[q * 256 + t] = make_uint2(sv, key);
    }
    __syncthreads();
    // local exclusive scan over 1024 buckets (4 per thread)
    int c4[4];
    int s = 0;
#pragma unroll
    for (int j = 0; j < 4; ++j) { c4[j] = h[t * 4 + j]; s += c4[j]; }
    w[t] = s;
    __syncthreads();
    for (int off = 1; off < 256; off <<= 1) {
        int tmp = (t >= off) ? w[t - off] : 0;
        __syncthreads();
        w[t] += tmp;
        __syncthreads();
    }
    int run = w[t] - s;              // local base of this thread's chunk
#pragma unroll
    for (int j = 0; j < 4; ++j) {
        int i = t * 4 + j;
        int c = c4[j];
        int lb = run; run += c;
        if (i < NBK) {
            int g = c ? atomicAdd(&coarse_cursor[i], c) : 0;
            delta[i] = g - lb;
            h[i] = lb;               // local cursor
        }
    }
    __syncthreads();
#pragma unroll
    for (int q = 0; q < QI; ++q) {
        uint2 p = pairs[q * 256 + t];
        if (p.y != 0xFFFFFFFFu) {
            int lp = atomicAdd(&h[p.y / KPB], 1);
            staged[lp] = p;
        }
    }
    __syncthreads();
    // coalesced write-out: consecutive staged entries in a bucket map to
    // consecutive global positions (global = delta[bucket] + local_idx)
    for (int j = t; j < KPB; j += 256) {
        uint2 p = staged[j];
        if (p.y != 0xFFFFFFFFu)
            coarse_buf[delta[p.y / KPB] + j] = p;
    }
}

// ---------------------------------------------- fill B (local sort+outputs) ---
// Stages the whole bucket's sorted_src in key order in LDS, then one linear
// (fully coalesced) copy out. Overflow beyond SCAP falls back to scatter.
__global__ __launch_bounds__(256) void fillB(
    const uint2* __restrict__ coarse_buf, const int* __restrict__ cscan,
    int* __restrict__ seg_off, float* __restrict__ cnt_inv,
    int* __restrict__ sorted_src, int M, int E, int NBK)
{
    __shared__ int cnt[KPB];         // 8 KB
    __shared__ int w[256];
    __shared__ int staged[SCAP];     // 24 KB
    const int t = threadIdx.x;
    const int b = blockIdx.x;
    const int kbase = b * KPB;
    const int nkeys = min(KPB, M - kbase);
    const int r0 = cscan[b], r1 = cscan[b + 1];

    for (int i = t; i < KPB; i += 256) cnt[i] = 0;
    __syncthreads();
    for (int e = r0 + t; e < r1; e += 256)
        atomicAdd(&cnt[coarse_buf[e].y - kbase], 1);
    __syncthreads();
    for (int i = t; i < nkeys; i += 256)
        cnt_inv[kbase + i] = 1.0f / fmaxf((float)cnt[i], 1.0f);
    int s = 0;
#pragma unroll
    for (int j = 0; j < QI; ++j) s += cnt[t * QI + j];
    w[t] = s;
    __syncthreads();
    for (int off = 1; off < 256; off <<= 1) {
        int tmp = (t >= off) ? w[t - off] : 0;
        __syncthreads();
        w[t] += tmp;
        __syncthreads();
    }
    int run = r0 + w[t] - s;
#pragma unroll
    for (int j = 0; j < QI; ++j) {
        int i = t * QI + j;
        int c = cnt[i];
        cnt[i] = run;
        if (i < nkeys) seg_off[kbase + i] = run;
        run += c;
    }
    if (b == NBK - 1 && t == 0) seg_off[M] = E;
    __syncthreads();
    for (int e = r0 + t; e < r1; e += 256) {
        uint2 p = coarse_buf[e];
        int pos = atomicAdd(&cnt[p.y - kbase], 1);
        int lp = pos - r0;
        if (lp < SCAP) staged[lp] = (int)p.x;
        else           sorted_src[pos] = (int)p.x;   // rare overflow fallback
    }
    __syncthreads();
    const int n = min(r1 - r0, SCAP);
    for (int j = t; j < n; j += 256)
        sorted_src[r0 + j] = staged[j];
}

// --------------------------------------------------------------- convert ---
__global__ __launch_bounds__(256) void conv_x_kernel(
    const float* __restrict__ x, unsigned short* __restrict__ xb, int n4)
{
    int i = blockIdx.x * 256 + threadIdx.x;
    if (i >= n4) return;
    float4 v = ((const float4*)x)[i];
    uint2 o;
    o.x = (unsigned)f2b(v.x) | ((unsigned)f2b(v.y) << 16);
    o.y = (unsigned)f2b(v.z) | ((unsigned)f2b(v.w) << 16);
    ((uint2*)xb)[i] = o;
}

// Weights in MFMA-fragment order: Wt[mat][(kt*8+ct)*64+lane][8 shorts],
// frag(lane) = { n = ct*16 + (lane&15), k = kt*32 + (lane>>4)*8 .. +8 }.
__global__ __launch_bounds__(256) void conv_w_kernel(
    const float* __restrict__ W, const float* __restrict__ root,
    unsigned short* __restrict__ Wt)
{
    int t = blockIdx.x * 256 + threadIdx.x;
    if (t >= 17 * 2048) return;
    int mat = t >> 11;
    int f = t & 2047;
    int lane = f & 63;
    int ctkt = f >> 6;
    int kt = ctkt >> 3;
    int ct = ctkt & 7;
    int n = ct * 16 + (lane & 15);
    int k = kt * 32 + (lane >> 4) * 8;
    const float* s = (mat < 16) ? (W + (size_t)mat * 16384) : root;
    uint4 o;
    o.x = (unsigned)f2b(s[(size_t)(k + 0) * ND + n]) | ((unsigned)f2b(s[(size_t)(k + 1) * ND + n]) << 16);
    o.y = (unsigned)f2b(s[(size_t)(k + 2) * ND + n]) | ((unsigned)f2b(s[(size_t)(k + 3) * ND + n]) << 16);
    o.z = (unsigned)f2b(s[(size_t)(k + 4) * ND + n]) | ((unsigned)f2b(s[(size_t)(k + 5) * ND + n]) << 16);
    o.w = (unsigned)f2b(s[(size_t)(k + 6) * ND + n]) | ((unsigned)f2b(s[(size_t)(k + 7) * ND + n]) << 16);
    *(uint4*)(Wt + (size_t)t * 8) = o;
}

// ----------------------------------------------------------- gather mean ---
__global__ __launch_bounds__(256) void gather_mean(
    const unsigned short* __restrict__ A,    // N x 128 bf16
    const int* __restrict__ seg_off,
    const int* __restrict__ sorted_src,
    const float* __restrict__ cnt_inv,
    unsigned short* __restrict__ msg,        // cc x N x 128 bf16
    int N, int r0, int ccN)
{
    int g = blockIdx.x * 16 + (threadIdx.x >> 4);
    if (g >= ccN) return;
    int l = threadIdx.x & 15;
    int s = r0 * N + g;
    int b0 = seg_off[s], e1 = seg_off[s + 1];
    float a0 = 0.f, a1 = 0.f, a2 = 0.f, a3 = 0.f, a4 = 0.f, a5 = 0.f, a6 = 0.f, a7 = 0.f;
    int e = b0;
    for (; e + 2 <= e1; e += 2) {
        int s0 = sorted_src[e];
        int s1 = sorted_src[e + 1];
        uint4 u0 = *(const uint4*)(A + (size_t)s0 * ND + l * 8);
        uint4 u1 = *(const uint4*)(A + (size_t)s1 * ND + l * 8);
        a0 += __uint_as_float(u0.x << 16); a1 += __uint_as_float(u0.x & 0xFFFF0000u);
        a2 += __uint_as_float(u0.y << 16); a3 += __uint_as_float(u0.y & 0xFFFF0000u);
        a4 += __uint_as_float(u0.z << 16); a5 += __uint_as_float(u0.z & 0xFFFF0000u);
        a6 += __uint_as_float(u0.w << 16); a7 += __uint_as_float(u0.w & 0xFFFF0000u);
        a0 += __uint_as_float(u1.x << 16); a1 += __uint_as_float(u1.x & 0xFFFF0000u);
        a2 += __uint_as_float(u1.y << 16); a3 += __uint_as_float(u1.y & 0xFFFF0000u);
        a4 += __uint_as_float(u1.z << 16); a5 += __uint_as_float(u1.z & 0xFFFF0000u);
        a6 += __uint_as_float(u1.w << 16); a7 += __uint_as_float(u1.w & 0xFFFF0000u);
    }
    if (e < e1) {
        int s0 = sorted_src[e];
        uint4 u0 = *(const uint4*)(A + (size_t)s0 * ND + l * 8);
        a0 += __uint_as_float(u0.x << 16); a1 += __uint_as_float(u0.x & 0xFFFF0000u);
        a2 += __uint_as_float(u0.y << 16); a3 += __uint_as_float(u0.y & 0xFFFF0000u);
        a4 += __uint_as_float(u0.z << 16); a5 += __uint_as_float(u0.z & 0xFFFF0000u);
        a6 += __uint_as_float(u0.w << 16); a7 += __uint_as_float(u0.w & 0xFFFF0000u);
    }
    float inv = cnt_inv[s];
    uint4 o;
    o.x = (unsigned)f2b(a0 * inv) | ((unsigned)f2b(a1 * inv) << 16);
    o.y = (unsigned)f2b(a2 * inv) | ((unsigned)f2b(a3 * inv) << 16);
    o.z = (unsigned)f2b(a4 * inv) | ((unsigned)f2b(a5 * inv) << 16);
    o.w = (unsigned)f2b(a6 * inv) | ((unsigned)f2b(a7 * inv) << 16);
    *(uint4*)(msg + (size_t)g * ND + l * 8) = o;
}

// -------------------------------------------------------------- mfma gemm ---
// 256 threads = 4 waves; block covers 128 rows: wave wv owns row-tiles at
// blk*128 + wv*16 (+0 and +64). Static-dbuf pipeline (R15): per phase,
// barrier -> issue next phase's loads (8 gload_lds -> other Bs, 8 A-loads ->
// other a regs) -> sched_barrier(0) -> setprio(1) -> 64 MFMA (each
// ds_read_b128 feeds both row-tiles) -> setprio(0).
#define PREFETCH(ph, BS, areg) do {                                              \
    const int rel_ = rel0 + (ph);                                                \
    const unsigned short* A_ = (rel_ < 0) ? xb : msg + (size_t)rel_ * (size_t)N * ND; \
    const int mat_ = (rel_ < 0) ? 16 : (c0 + rel_);                              \
    const unsigned short* Bsrc_ = Wt + (size_t)mat_ * 2048 * 8;                  \
    _Pragma("unroll")                                                            \
    for (int i_ = 0; i_ < 8; ++i_)                                               \
        gload16(Bsrc_ + (size_t)(tid + i_ * 256) * 8, BS + (size_t)(tid + i_ * 256) * 8); \
    _Pragma("unroll")                                                            \
    for (int rt_ = 0; rt_ < 2; ++rt_) {                                          \
        const int ar_ = arow + rt_ * 64;                                         \
        _Pragma("unroll")                                                        \
        for (int kt_ = 0; kt_ < 4; ++kt_) {                                      \
            const bf16x8* ap_ = (const bf16x8*)(A_ + (size_t)ar_ * ND + kt_ * 32 + quad * 8); \
            areg[rt_][kt_] = (ar_ < N) ? *ap_ : zfrag;                           \
        }                                                                        \
    }                                                                            \
} while (0)

#define COMPUTE(BS, areg) do {                                                   \
    __builtin_amdgcn_s_setprio(1);                                               \
    _Pragma("unroll")                                                            \
    for (int kt_ = 0; kt_ < 4; ++kt_) {                                          \
        _Pragma("unroll")                                                        \
        for (int ct_ = 0; ct_ < 8; ++ct_) {                                      \
            bf16x8 b_ = *(const bf16x8*)(BS + (size_t)((kt_ * 8 + ct_) * 64 + lane) * 8); \
            acc[0][ct_] = __builtin_amdgcn_mfma_f32_16x16x32_bf16(areg[0][kt_], b_, acc[0][ct_], 0, 0, 0); \
            acc[1][ct_] = __builtin_amdgcn_mfma_f32_16x16x32_bf16(areg[1][kt_], b_, acc[1][ct_], 0, 0, 0); \
        }                                                                        \
    }                                                                            \
    __builtin_amdgcn_s_setprio(0);                                               \
} while (0)

__global__ __launch_bounds__(256) void gemm_mfma(
    const unsigned short* __restrict__ msg,   // cc x N x 128 bf16
    const unsigned short* __restrict__ xb,    // N x 128 bf16 (root operand)
    const unsigned short* __restrict__ Wt,    // [17][2048][8] swizzled bf16
    const float* __restrict__ bias,
    float* __restrict__ acc_buf,              // N x 128 f32 (multi-pass)
    unsigned short* __restrict__ out_bf,      // layer-1 dest or null
    float* __restrict__ out_f32,              // layer-2 dest or null
    int N, int c0, int cc, int include_root, int load_acc, int finalize)
{
    __shared__ __align__(16) unsigned short Bs0[2048 * 8];   // 32 KB
    __shared__ __align__(16) unsigned short Bs1[2048 * 8];   // 32 KB
    const int tid = threadIdx.x;
    const int lane = tid & 63;
    const int wv = tid >> 6;
    const int quad = lane >> 4;
    const int l16 = lane & 15;
    const int m0 = blockIdx.x * 128 + wv * 16;
    const int arow = m0 + l16;

    f32x4 acc[2][8];
    if (load_acc) {
#pragma unroll
        for (int rt = 0; rt < 2; ++rt)
#pragma unroll
            for (int ct = 0; ct < 8; ++ct)
#pragma unroll
                for (int rg = 0; rg < 4; ++rg) {
                    int r = m0 + rt * 64 + quad * 4 + rg;
                    acc[rt][ct][rg] = (r < N) ? acc_buf[(size_t)r * ND + ct * 16 + l16] : 0.f;
                }
    } else {
#pragma unroll
        for (int rt = 0; rt < 2; ++rt)
#pragma unroll
            for (int ct = 0; ct < 8; ++ct) { f32x4 z = {0.f, 0.f, 0.f, 0.f}; acc[rt][ct] = z; }
    }

    const int rel0 = include_root ? -1 : 0;
    const int P = cc - rel0;                  // number of phases
    const bf16x8 zfrag = {0, 0, 0, 0, 0, 0, 0, 0};
    bf16x8 a0[2][4], a1[2][4];

    PREFETCH(0, Bs0, a0);
    int p = 0;
    for (; p + 2 <= P; p += 2) {
        __syncthreads();                       // drains prev prefetch (aged 1 phase)
        if (p + 1 < P) { PREFETCH(p + 1, Bs1, a1); }
        __builtin_amdgcn_sched_barrier(0);     // keep issues above the MFMA cluster
        COMPUTE(Bs0, a0);
        __syncthreads();
        if (p + 2 < P) { PREFETCH(p + 2, Bs0, a0); }
        __builtin_amdgcn_sched_barrier(0);
        COMPUTE(Bs1, a1);
    }
    if (p < P) {                               // odd P tail
        __syncthreads();
        COMPUTE(Bs0, a0);
    }

    if (!finalize) {
#pragma unroll
        for (int rt = 0; rt < 2; ++rt)
#pragma unroll
            for (int ct = 0; ct < 8; ++ct)
#pragma unroll
                for (int rg = 0; rg < 4; ++rg) {
                    int r = m0 + rt * 64 + quad * 4 + rg;
                    if (r < N) acc_buf[(size_t)r * ND + ct * 16 + l16] = acc[rt][ct][rg];
                }
    } else {
#pragma unroll
        for (int rt = 0; rt < 2; ++rt)
#pragma unroll
            for (int ct = 0; ct < 8; ++ct) {
                float bb = bias[ct * 16 + l16];
#pragma unroll
                for (int rg = 0; rg < 4; ++rg) {
                    int r = m0 + rt * 64 + quad * 4 + rg;
                    if (r < N) {
                        float v = fmaxf(acc[rt][ct][rg] + bb, 0.f);
                        if (out_bf) out_bf[(size_t)r * ND + ct * 16 + l16] = f2b(v);
                        else        __builtin_nontemporal_store(v, &out_f32[(size_t)r * ND + ct * 16 + l16]);
                    }
                }
            }
    }
}

// ----------------------------------------------------------------- launch ---
extern "C" void kernel_launch(void* const* d_in, const int* in_sizes, int n_in,
                              void* d_out, int out_size, void* d_ws, size_t ws_size,
                              hipStream_t stream) {
    const float* x     = (const float*)d_in[0];
    const int*   eidx  = (const int*)d_in[1];
    const int*   etype = (const int*)d_in[2];
    const float* W1    = (const float*)d_in[3];
    const float* root1 = (const float*)d_in[4];
    const float* b1    = (const float*)d_in[5];
    const float* W2    = (const float*)d_in[6];
    const float* root2 = (const float*)d_in[7];
    const float* b2    = (const float*)d_in[8];
    float* out = (float*)d_out;

    const int N = in_sizes[0] / ND;
    const int E = in_sizes[2];
    const int M = NR * N;
    const int NBK = (M + KPB - 1) / KPB;

    const int* src = eidx;
    const int* dst = eidx + E;

    // --- workspace carve-up: fixed (~41 MB) + union region ---
    char* p = (char*)d_ws;
    auto carve = [&](size_t bytes) { char* q = p; p += (bytes + 255) & ~(size_t)255; return q; };
    unsigned short* h_bf    = (unsigned short*)carve((size_t)N * ND * 2);
    unsigned short* x_bf    = (unsigned short*)carve((size_t)N * ND * 2);
    unsigned short* Wt1     = (unsigned short*)carve((size_t)17 * 2048 * 8 * 2);
    unsigned short* Wt2     = (unsigned short*)carve((size_t)17 * 2048 * 8 * 2);
    int*   seg_off          = (int*)  carve((size_t)(M + 1) * 4);
    float* cnt_inv          = (float*)carve((size_t)M * 4);
    int*   sorted_src       = (int*)  carve((size_t)E * 4);
    int*   coarse_cnt       = (int*)  carve(1024 * 4);
    int*   cscan            = (int*)  carve(1025 * 4);
    int*   coarse_cursor    = (int*)  carve(1024 * 4);

    // union region: coarse_buf (sort phase) OR msg [+ acc if C<16] (gemm phase)
    size_t fixed = (size_t)(p - (char*)d_ws);
    size_t remain = (ws_size > fixed) ? ws_size - fixed : 0;
    size_t chunk_bytes = (size_t)N * ND * 2;
    size_t acc_bytes   = (size_t)N * ND * 4;
    int C = 2;
    if (remain >= 16 * chunk_bytes + 512) C = 16;
    else if (remain >= 8 * chunk_bytes + acc_bytes + 512) C = 8;
    else if (remain >= 4 * chunk_bytes + acc_bytes + 512) C = 4;
    uint2* coarse_buf       = (uint2*)p;                 // E*8 <= union size
    unsigned short* msg     = (unsigned short*)carve((size_t)C * chunk_bytes);
    float* acc              = (float*)((C < 16) ? carve(acc_bytes) : (char*)p);

    const int eb4 = (E + KPB - 1) / KPB;
    const int gemm_blocks = (N + 127) / 128;

    // --- two-level counting sort by (rel, dst) ---
    hipMemsetAsync(coarse_cnt, 0, 1024 * 4, stream);
    coarse_hist<<<eb4, 256, 0, stream>>>(dst, etype, coarse_cnt, E, N, NBK);
    coarse_scan<<<1, 1024, 0, stream>>>(coarse_cnt, cscan, coarse_cursor, NBK, E);
    fillA<<<eb4, 256, 0, stream>>>(src, dst, etype, coarse_cursor, coarse_buf, E, N, NBK);
    fillB<<<NBK, 256, 0, stream>>>(coarse_buf, cscan, seg_off, cnt_inv, sorted_src, M, E, NBK);

    // --- bf16 conversions ---
    conv_x_kernel<<<((N * ND / 4) + 255) / 256, 256, 0, stream>>>(x, x_bf, N * ND / 4);
    conv_w_kernel<<<(17 * 2048 + 255) / 256, 256, 0, stream>>>(W1, root1, Wt1);
    conv_w_kernel<<<(17 * 2048 + 255) / 256, 256, 0, stream>>>(W2, root2, Wt2);

    // --- two layers, C relations per pass ---
    for (int layer = 0; layer < 2; ++layer) {
        const unsigned short* A  = (layer == 0) ? x_bf : h_bf;
        const unsigned short* Wt = (layer == 0) ? Wt1  : Wt2;
        const float* biasp       = (layer == 0) ? b1   : b2;

        for (int c0 = 0; c0 < NR; c0 += C) {
            int cc = (NR - c0 < C) ? (NR - c0) : C;
            int ccN = cc * N;
            gather_mean<<<(ccN + 15) / 16, 256, 0, stream>>>(
                A, seg_off, sorted_src, cnt_inv, msg, N, c0, ccN);
            int fin = (c0 + cc == NR) ? 1 : 0;
            gemm_mfma<<<gemm_blocks, 256, 0, stream>>>(
                msg, A, Wt, biasp, acc,
                (fin && layer == 0) ? h_bf : (unsigned short*)nullptr,
                (fin && layer == 1) ? out : (float*)nullptr,
                N, c0, cc, c0 == 0 ? 1 : 0, c0 > 0 ? 1 : 0, fin);
        }
    }
}

// Round 14
// 460.612 us; speedup vs baseline: 1.1004x; 1.1004x over previous
//
#include <hip/hip_runtime.h>

// RGCN 2-layer forward for MI355X (gfx950). N=50000, D=128, R=16, E=1600000.
//
// Round-22: revert R21's sort LDS-staging (regressed 461.6 -> 506.8: sort is
// not scatter-write-bound; staging cost occupancy + barriers). Exact R20
// sort/gather/gemm (461.6us best). One safe change: the three conversion
// kernels (x, W1, W2) merge into a single conv_all dispatch (block-range
// dispatch) - saves 2 launch gaps and lets the small W conversions overlap
// the x conversion instead of serializing behind it.
//
// ws: h_bf | x_bf | Wt1 | Wt2 | seg_off | cnt_inv | sorted_src | ctl |
//     union( coarse_buf , msg(C*N*128 bf16) + acc(N*128 f32 if C<16) )

#define ND 128
#define NR 16
#define KPB 2048              // keys per coarse bucket
#define QI (KPB / 256)        // edge iters per block in hist/fillA

typedef __attribute__((ext_vector_type(8))) short bf16x8;
typedef __attribute__((ext_vector_type(4))) float f32x4;

__device__ __forceinline__ unsigned short f2b(float f) {
    unsigned u = __float_as_uint(f);
    u += 0x7FFFu + ((u >> 16) & 1u);          // round-to-nearest-even
    return (unsigned short)(u >> 16);
}

// async global->LDS, 16 bytes per lane (wave: 1 KB per instruction)
__device__ __forceinline__ void gload16(const unsigned short* g, unsigned short* l) {
    __builtin_amdgcn_global_load_lds(
        (__attribute__((address_space(1))) void*)g,
        (__attribute__((address_space(3))) void*)l, 16, 0, 0);
}

// ------------------------------------------------------------ coarse hist ---
__global__ __launch_bounds__(256) void coarse_hist(
    const int* __restrict__ dst, const int* __restrict__ rel,
    int* __restrict__ coarse_cnt, int E, int N, int NBK)
{
    __shared__ int h[1024];
    const int t = threadIdx.x;
    for (int i = t; i < NBK; i += 256) h[i] = 0;
    __syncthreads();
#pragma unroll
    for (int q = 0; q < QI; ++q) {
        int e = blockIdx.x * KPB + q * 256 + t;
        if (e < E) {
            int key = rel[e] * N + dst[e];
            atomicAdd(&h[key / KPB], 1);
        }
    }
    __syncthreads();
    for (int i = t; i < NBK; i += 256)
        if (h[i]) atomicAdd(&coarse_cnt[i], h[i]);
}

// ------------------------------------------------------------ coarse scan ---
__global__ __launch_bounds__(1024) void coarse_scan(
    const int* __restrict__ coarse_cnt, int* __restrict__ cscan,
    int* __restrict__ coarse_cursor, int NBK, int E)
{
    __shared__ int sdata[1024];
    const int t = threadIdx.x;
    int v = (t < NBK) ? coarse_cnt[t] : 0;
    sdata[t] = v;
    __syncthreads();
    for (int off = 1; off < 1024; off <<= 1) {
        int tmp = (t >= off) ? sdata[t - off] : 0;
        __syncthreads();
        sdata[t] += tmp;
        __syncthreads();
    }
    if (t < NBK) {
        int excl = sdata[t] - v;
        cscan[t] = excl;
        coarse_cursor[t] = excl;
    }
    if (t == 0) cscan[NBK] = E;
}

// --------------------------------------------------------- fill A (bucket) ---
__global__ __launch_bounds__(256) void fillA(
    const int* __restrict__ src, const int* __restrict__ dst,
    const int* __restrict__ rel, int* __restrict__ coarse_cursor,
    uint2* __restrict__ coarse_buf, int E, int N, int NBK)
{
    __shared__ uint2 pairs[KPB];
    __shared__ int h[1024];
    const int t = threadIdx.x;
    for (int i = t; i < NBK; i += 256) h[i] = 0;
    __syncthreads();
#pragma unroll
    for (int q = 0; q < QI; ++q) {
        int e = blockIdx.x * KPB + q * 256 + t;
        unsigned key = 0xFFFFFFFFu, sv = 0;
        if (e < E) {
            key = (unsigned)(rel[e] * N + dst[e]);
            sv = (unsigned)src[e];
            atomicAdd(&h[key / KPB], 1);
        }
        pairs[q * 256 + t] = make_uint2(sv, key);
    }
    __syncthreads();
    for (int i = t; i < NBK; i += 256) {
        int c = h[i];
        h[i] = c ? atomicAdd(&coarse_cursor[i], c) : 0;
    }
    __syncthreads();
#pragma unroll
    for (int q = 0; q < QI; ++q) {
        uint2 p = pairs[q * 256 + t];
        if (p.y != 0xFFFFFFFFu) {
            int pos = atomicAdd(&h[p.y / KPB], 1);
            coarse_buf[pos] = p;
        }
    }
}

// ---------------------------------------------- fill B (local sort+outputs) ---
__global__ __launch_bounds__(256) void fillB(
    const uint2* __restrict__ coarse_buf, const int* __restrict__ cscan,
    int* __restrict__ seg_off, float* __restrict__ cnt_inv,
    int* __restrict__ sorted_src, int M, int E, int NBK)
{
    __shared__ int cnt[KPB];
    __shared__ int w[256];
    const int t = threadIdx.x;
    const int b = blockIdx.x;
    const int kbase = b * KPB;
    const int nkeys = min(KPB, M - kbase);
    const int r0 = cscan[b], r1 = cscan[b + 1];

    for (int i = t; i < KPB; i += 256) cnt[i] = 0;
    __syncthreads();
    for (int e = r0 + t; e < r1; e += 256)
        atomicAdd(&cnt[coarse_buf[e].y - kbase], 1);
    __syncthreads();
    for (int i = t; i < nkeys; i += 256)
        cnt_inv[kbase + i] = 1.0f / fmaxf((float)cnt[i], 1.0f);
    int s = 0;
#pragma unroll
    for (int j = 0; j < QI; ++j) s += cnt[t * QI + j];
    w[t] = s;
    __syncthreads();
    for (int off = 1; off < 256; off <<= 1) {
        int tmp = (t >= off) ? w[t - off] : 0;
        __syncthreads();
        w[t] += tmp;
        __syncthreads();
    }
    int run = r0 + w[t] - s;
#pragma unroll
    for (int j = 0; j < QI; ++j) {
        int i = t * QI + j;
        int c = cnt[i];
        cnt[i] = run;
        if (i < nkeys) seg_off[kbase + i] = run;
        run += c;
    }
    if (b == NBK - 1 && t == 0) seg_off[M] = E;
    __syncthreads();
    for (int e = r0 + t; e < r1; e += 256) {
        uint2 p = coarse_buf[e];
        int pos = atomicAdd(&cnt[p.y - kbase], 1);
        sorted_src[pos] = (int)p.x;
    }
}

// ------------------------------------------------- merged conversions -------
// Blocks [0, xblocks): x f32 -> bf16.  Blocks [xblocks, xblocks+272):
// W1/root1 then W2/root2 into MFMA-fragment order:
// Wt[mat][(kt*8+ct)*64+lane][8], frag(lane) = { n = ct*16+(lane&15),
// k = kt*32+(lane>>4)*8 .. +8 }.
__global__ __launch_bounds__(256) void conv_all(
    const float* __restrict__ x, unsigned short* __restrict__ xb, int n4,
    const float* __restrict__ W1, const float* __restrict__ root1, unsigned short* __restrict__ Wt1,
    const float* __restrict__ W2, const float* __restrict__ root2, unsigned short* __restrict__ Wt2)
{
    const int xblocks = (n4 + 255) / 256;
    const int b = blockIdx.x;
    if (b < xblocks) {
        int i = b * 256 + threadIdx.x;
        if (i >= n4) return;
        float4 v = ((const float4*)x)[i];
        uint2 o;
        o.x = (unsigned)f2b(v.x) | ((unsigned)f2b(v.y) << 16);
        o.y = (unsigned)f2b(v.z) | ((unsigned)f2b(v.w) << 16);
        ((uint2*)xb)[i] = o;
        return;
    }
    int t = (b - xblocks) * 256 + threadIdx.x;      // 0 .. 2*17*2048-1
    const int which = t / (17 * 2048);
    t -= which * 17 * 2048;
    const float* W    = which ? W2    : W1;
    const float* root = which ? root2 : root1;
    unsigned short* Wt = which ? Wt2  : Wt1;
    int mat = t >> 11;
    int f = t & 2047;
    int lane = f & 63;
    int ctkt = f >> 6;
    int kt = ctkt >> 3;
    int ct = ctkt & 7;
    int n = ct * 16 + (lane & 15);
    int k = kt * 32 + (lane >> 4) * 8;
    const float* s = (mat < 16) ? (W + (size_t)mat * 16384) : root;
    uint4 o;
    o.x = (unsigned)f2b(s[(size_t)(k + 0) * ND + n]) | ((unsigned)f2b(s[(size_t)(k + 1) * ND + n]) << 16);
    o.y = (unsigned)f2b(s[(size_t)(k + 2) * ND + n]) | ((unsigned)f2b(s[(size_t)(k + 3) * ND + n]) << 16);
    o.z = (unsigned)f2b(s[(size_t)(k + 4) * ND + n]) | ((unsigned)f2b(s[(size_t)(k + 5) * ND + n]) << 16);
    o.w = (unsigned)f2b(s[(size_t)(k + 6) * ND + n]) | ((unsigned)f2b(s[(size_t)(k + 7) * ND + n]) << 16);
    *(uint4*)(Wt + (size_t)t * 8) = o;
}

// ----------------------------------------------------------- gather mean ---
__global__ __launch_bounds__(256) void gather_mean(
    const unsigned short* __restrict__ A,    // N x 128 bf16
    const int* __restrict__ seg_off,
    const int* __restrict__ sorted_src,
    const float* __restrict__ cnt_inv,
    unsigned short* __restrict__ msg,        // cc x N x 128 bf16
    int N, int r0, int ccN)
{
    int g = blockIdx.x * 16 + (threadIdx.x >> 4);
    if (g >= ccN) return;
    int l = threadIdx.x & 15;
    int s = r0 * N + g;
    int b0 = seg_off[s], e1 = seg_off[s + 1];
    float a0 = 0.f, a1 = 0.f, a2 = 0.f, a3 = 0.f, a4 = 0.f, a5 = 0.f, a6 = 0.f, a7 = 0.f;
    int e = b0;
    for (; e + 2 <= e1; e += 2) {
        int s0 = sorted_src[e];
        int s1 = sorted_src[e + 1];
        uint4 u0 = *(const uint4*)(A + (size_t)s0 * ND + l * 8);
        uint4 u1 = *(const uint4*)(A + (size_t)s1 * ND + l * 8);
        a0 += __uint_as_float(u0.x << 16); a1 += __uint_as_float(u0.x & 0xFFFF0000u);
        a2 += __uint_as_float(u0.y << 16); a3 += __uint_as_float(u0.y & 0xFFFF0000u);
        a4 += __uint_as_float(u0.z << 16); a5 += __uint_as_float(u0.z & 0xFFFF0000u);
        a6 += __uint_as_float(u0.w << 16); a7 += __uint_as_float(u0.w & 0xFFFF0000u);
        a0 += __uint_as_float(u1.x << 16); a1 += __uint_as_float(u1.x & 0xFFFF0000u);
        a2 += __uint_as_float(u1.y << 16); a3 += __uint_as_float(u1.y & 0xFFFF0000u);
        a4 += __uint_as_float(u1.z << 16); a5 += __uint_as_float(u1.z & 0xFFFF0000u);
        a6 += __uint_as_float(u1.w << 16); a7 += __uint_as_float(u1.w & 0xFFFF0000u);
    }
    if (e < e1) {
        int s0 = sorted_src[e];
        uint4 u0 = *(const uint4*)(A + (size_t)s0 * ND + l * 8);
        a0 += __uint_as_float(u0.x << 16); a1 += __uint_as_float(u0.x & 0xFFFF0000u);
        a2 += __uint_as_float(u0.y << 16); a3 += __uint_as_float(u0.y & 0xFFFF0000u);
        a4 += __uint_as_float(u0.z << 16); a5 += __uint_as_float(u0.z & 0xFFFF0000u);
        a6 += __uint_as_float(u0.w << 16); a7 += __uint_as_float(u0.w & 0xFFFF0000u);
    }
    float inv = cnt_inv[s];
    uint4 o;
    o.x = (unsigned)f2b(a0 * inv) | ((unsigned)f2b(a1 * inv) << 16);
    o.y = (unsigned)f2b(a2 * inv) | ((unsigned)f2b(a3 * inv) << 16);
    o.z = (unsigned)f2b(a4 * inv) | ((unsigned)f2b(a5 * inv) << 16);
    o.w = (unsigned)f2b(a6 * inv) | ((unsigned)f2b(a7 * inv) << 16);
    *(uint4*)(msg + (size_t)g * ND + l * 8) = o;
}

// -------------------------------------------------------------- mfma gemm ---
// 256 threads = 4 waves; block covers 128 rows: wave wv owns row-tiles at
// blk*128 + wv*16 (+0 and +64). Static-dbuf pipeline (R15): per phase,
// barrier -> issue next phase's loads (8 gload_lds -> other Bs, 8 A-loads ->
// other a regs) -> sched_barrier(0) -> setprio(1) -> 64 MFMA (each
// ds_read_b128 feeds both row-tiles) -> setprio(0).
#define PREFETCH(ph, BS, areg) do {                                              \
    const int rel_ = rel0 + (ph);                                                \
    const unsigned short* A_ = (rel_ < 0) ? xb : msg + (size_t)rel_ * (size_t)N * ND; \
    const int mat_ = (rel_ < 0) ? 16 : (c0 + rel_);                              \
    const unsigned short* Bsrc_ = Wt + (size_t)mat_ * 2048 * 8;                  \
    _Pragma("unroll")                                                            \
    for (int i_ = 0; i_ < 8; ++i_)                                               \
        gload16(Bsrc_ + (size_t)(tid + i_ * 256) * 8, BS + (size_t)(tid + i_ * 256) * 8); \
    _Pragma("unroll")                                                            \
    for (int rt_ = 0; rt_ < 2; ++rt_) {                                          \
        const int ar_ = arow + rt_ * 64;                                         \
        _Pragma("unroll")                                                        \
        for (int kt_ = 0; kt_ < 4; ++kt_) {                                      \
            const bf16x8* ap_ = (const bf16x8*)(A_ + (size_t)ar_ * ND + kt_ * 32 + quad * 8); \
            areg[rt_][kt_] = (ar_ < N) ? *ap_ : zfrag;                           \
        }                                                                        \
    }                                                                            \
} while (0)

#define COMPUTE(BS, areg) do {                                                   \
    __builtin_amdgcn_s_setprio(1);                                               \
    _Pragma("unroll")                                                            \
    for (int kt_ = 0; kt_ < 4; ++kt_) {                                          \
        _Pragma("unroll")                                                        \
        for (int ct_ = 0; ct_ < 8; ++ct_) {                                      \
            bf16x8 b_ = *(const bf16x8*)(BS + (size_t)((kt_ * 8 + ct_) * 64 + lane) * 8); \
            acc[0][ct_] = __builtin_amdgcn_mfma_f32_16x16x32_bf16(areg[0][kt_], b_, acc[0][ct_], 0, 0, 0); \
            acc[1][ct_] = __builtin_amdgcn_mfma_f32_16x16x32_bf16(areg[1][kt_], b_, acc[1][ct_], 0, 0, 0); \
        }                                                                        \
    }                                                                            \
    __builtin_amdgcn_s_setprio(0);                                               \
} while (0)

__global__ __launch_bounds__(256) void gemm_mfma(
    const unsigned short* __restrict__ msg,   // cc x N x 128 bf16
    const unsigned short* __restrict__ xb,    // N x 128 bf16 (root operand)
    const unsigned short* __restrict__ Wt,    // [17][2048][8] swizzled bf16
    const float* __restrict__ bias,
    float* __restrict__ acc_buf,              // N x 128 f32 (multi-pass)
    unsigned short* __restrict__ out_bf,      // layer-1 dest or null
    float* __restrict__ out_f32,              // layer-2 dest or null
    int N, int c0, int cc, int include_root, int load_acc, int finalize)
{
    __shared__ __align__(16) unsigned short Bs0[2048 * 8];   // 32 KB
    __shared__ __align__(16) unsigned short Bs1[2048 * 8];   // 32 KB
    const int tid = threadIdx.x;
    const int lane = tid & 63;
    const int wv = tid >> 6;
    const int quad = lane >> 4;
    const int l16 = lane & 15;
    const int m0 = blockIdx.x * 128 + wv * 16;
    const int arow = m0 + l16;

    f32x4 acc[2][8];
    if (load_acc) {
#pragma unroll
        for (int rt = 0; rt < 2; ++rt)
#pragma unroll
            for (int ct = 0; ct < 8; ++ct)
#pragma unroll
                for (int rg = 0; rg < 4; ++rg) {
                    int r = m0 + rt * 64 + quad * 4 + rg;
                    acc[rt][ct][rg] = (r < N) ? acc_buf[(size_t)r * ND + ct * 16 + l16] : 0.f;
                }
    } else {
#pragma unroll
        for (int rt = 0; rt < 2; ++rt)
#pragma unroll
            for (int ct = 0; ct < 8; ++ct) { f32x4 z = {0.f, 0.f, 0.f, 0.f}; acc[rt][ct] = z; }
    }

    const int rel0 = include_root ? -1 : 0;
    const int P = cc - rel0;                  // number of phases
    const bf16x8 zfrag = {0, 0, 0, 0, 0, 0, 0, 0};
    bf16x8 a0[2][4], a1[2][4];

    PREFETCH(0, Bs0, a0);
    int p = 0;
    for (; p + 2 <= P; p += 2) {
        __syncthreads();                       // drains prev prefetch (aged 1 phase)
        if (p + 1 < P) { PREFETCH(p + 1, Bs1, a1); }
        __builtin_amdgcn_sched_barrier(0);     // keep issues above the MFMA cluster
        COMPUTE(Bs0, a0);
        __syncthreads();
        if (p + 2 < P) { PREFETCH(p + 2, Bs0, a0); }
        __builtin_amdgcn_sched_barrier(0);
        COMPUTE(Bs1, a1);
    }
    if (p < P) {                               // odd P tail
        __syncthreads();
        COMPUTE(Bs0, a0);
    }

    if (!finalize) {
#pragma unroll
        for (int rt = 0; rt < 2; ++rt)
#pragma unroll
            for (int ct = 0; ct < 8; ++ct)
#pragma unroll
                for (int rg = 0; rg < 4; ++rg) {
                    int r = m0 + rt * 64 + quad * 4 + rg;
                    if (r < N) acc_buf[(size_t)r * ND + ct * 16 + l16] = acc[rt][ct][rg];
                }
    } else {
#pragma unroll
        for (int rt = 0; rt < 2; ++rt)
#pragma unroll
            for (int ct = 0; ct < 8; ++ct) {
                float bb = bias[ct * 16 + l16];
#pragma unroll
                for (int rg = 0; rg < 4; ++rg) {
                    int r = m0 + rt * 64 + quad * 4 + rg;
                    if (r < N) {
                        float v = fmaxf(acc[rt][ct][rg] + bb, 0.f);
                        if (out_bf) out_bf[(size_t)r * ND + ct * 16 + l16] = f2b(v);
                        else        __builtin_nontemporal_store(v, &out_f32[(size_t)r * ND + ct * 16 + l16]);
                    }
                }
            }
    }
}

// ----------------------------------------------------------------- launch ---
extern "C" void kernel_launch(void* const* d_in, const int* in_sizes, int n_in,
                              void* d_out, int out_size, void* d_ws, size_t ws_size,
                              hipStream_t stream) {
    const float* x     = (const float*)d_in[0];
    const int*   eidx  = (const int*)d_in[1];
    const int*   etype = (const int*)d_in[2];
    const float* W1    = (const float*)d_in[3];
    const float* root1 = (const float*)d_in[4];
    const float* b1    = (const float*)d_in[5];
    const float* W2    = (const float*)d_in[6];
    const float* root2 = (const float*)d_in[7];
    const float* b2    = (const float*)d_in[8];
    float* out = (float*)d_out;

    const int N = in_sizes[0] / ND;
    const int E = in_sizes[2];
    const int M = NR * N;
    const int NBK = (M + KPB - 1) / KPB;

    const int* src = eidx;
    const int* dst = eidx + E;

    // --- workspace carve-up: fixed (~41 MB) + union region ---
    char* p = (char*)d_ws;
    auto carve = [&](size_t bytes) { char* q = p; p += (bytes + 255) & ~(size_t)255; return q; };
    unsigned short* h_bf    = (unsigned short*)carve((size_t)N * ND * 2);
    unsigned short* x_bf    = (unsigned short*)carve((size_t)N * ND * 2);
    unsigned short* Wt1     = (unsigned short*)carve((size_t)17 * 2048 * 8 * 2);
    unsigned short* Wt2     = (unsigned short*)carve((size_t)17 * 2048 * 8 * 2);
    int*   seg_off          = (int*)  carve((size_t)(M + 1) * 4);
    float* cnt_inv          = (float*)carve((size_t)M * 4);
    int*   sorted_src       = (int*)  carve((size_t)E * 4);
    int*   coarse_cnt       = (int*)  carve(1024 * 4);
    int*   cscan            = (int*)  carve(1025 * 4);
    int*   coarse_cursor    = (int*)  carve(1024 * 4);

    // union region: coarse_buf (sort phase) OR msg [+ acc if C<16] (gemm phase)
    size_t fixed = (size_t)(p - (char*)d_ws);
    size_t remain = (ws_size > fixed) ? ws_size - fixed : 0;
    size_t chunk_bytes = (size_t)N * ND * 2;
    size_t acc_bytes   = (size_t)N * ND * 4;
    int C = 2;
    if (remain >= 16 * chunk_bytes + 512) C = 16;
    else if (remain >= 8 * chunk_bytes + acc_bytes + 512) C = 8;
    else if (remain >= 4 * chunk_bytes + acc_bytes + 512) C = 4;
    uint2* coarse_buf       = (uint2*)p;                 // E*8 <= union size
    unsigned short* msg     = (unsigned short*)carve((size_t)C * chunk_bytes);
    float* acc              = (float*)((C < 16) ? carve(acc_bytes) : (char*)p);

    const int eb4 = (E + KPB - 1) / KPB;
    const int gemm_blocks = (N + 127) / 128;
    const int n4 = N * ND / 4;
    const int xblocks = (n4 + 255) / 256;
    const int conv_blocks = xblocks + (2 * 17 * 2048 + 255) / 256;

    // --- two-level counting sort by (rel, dst) ---
    hipMemsetAsync(coarse_cnt, 0, 1024 * 4, stream);
    coarse_hist<<<eb4, 256, 0, stream>>>(dst, etype, coarse_cnt, E, N, NBK);
    coarse_scan<<<1, 1024, 0, stream>>>(coarse_cnt, cscan, coarse_cursor, NBK, E);
    fillA<<<eb4, 256, 0, stream>>>(src, dst, etype, coarse_cursor, coarse_buf, E, N, NBK);
    fillB<<<NBK, 256, 0, stream>>>(coarse_buf, cscan, seg_off, cnt_inv, sorted_src, M, E, NBK);

    // --- merged bf16 conversions (x + W1 + W2, one dispatch) ---
    conv_all<<<conv_blocks, 256, 0, stream>>>(
        x, x_bf, n4, W1, root1, Wt1, W2, root2, Wt2);

    // --- two layers, C relations per pass ---
    for (int layer = 0; layer < 2; ++layer) {
        const unsigned short* A  = (layer == 0) ? x_bf : h_bf;
        const unsigned short* Wt = (layer == 0) ? Wt1  : Wt2;
        const float* biasp       = (layer == 0) ? b1   : b2;

        for (int c0 = 0; c0 < NR; c0 += C) {
            int cc = (NR - c0 < C) ? (NR - c0) : C;
            int ccN = cc * N;
            gather_mean<<<(ccN + 15) / 16, 256, 0, stream>>>(
                A, seg_off, sorted_src, cnt_inv, msg, N, c0, ccN);
            int fin = (c0 + cc == NR) ? 1 : 0;
            gemm_mfma<<<gemm_blocks, 256, 0, stream>>>(
                msg, A, Wt, biasp, acc,
                (fin && layer == 0) ? h_bf : (unsigned short*)nullptr,
                (fin && layer == 1) ? out : (float*)nullptr,
                N, c0, cc, c0 == 0 ? 1 : 0, c0 > 0 ? 1 : 0, fin);
        }
    }
}